// Round 2
// baseline (616.012 us; speedup 1.0000x reference)
//
#include <hip/hip_runtime.h>
#include <hip/hip_bf16.h>
#include <math.h>

#define IN_F  256
#define OUT_F 64
#define NPW   8      // nodes per wave in GEMM

// ---------------------------------------------------------------------------
// 1. CSR row_ptr from sorted rows: row_ptr[r] = lower_bound(rows, r)
// ---------------------------------------------------------------------------
__global__ void rowptr_kernel(const int* __restrict__ rows,
                              int* __restrict__ row_ptr,
                              int n_rows, int n_edges) {
    int r = blockIdx.x * blockDim.x + threadIdx.x;
    if (r > n_rows) return;
    if (r == n_rows) { row_ptr[n_rows] = n_edges; return; }
    int lo = 0, hi = n_edges;
    while (lo < hi) {
        int mid = (lo + hi) >> 1;
        if (rows[mid] < r) lo = mid + 1; else hi = mid;
    }
    row_ptr[r] = lo;
}

// ---------------------------------------------------------------------------
// 2. support = tanh(features @ weight)  — fp32 vector GEMM.
//    One wave: lane = output col (64), NPW nodes; W staged in LDS
//    (w_sh[k*64+col]: lanes l and l+32 alias one bank -> free 2-way).
//    Feature reads are wave-uniform -> scalar loads.
// ---------------------------------------------------------------------------
__global__ __launch_bounds__(256) void gemm_tanh_kernel(
    const float* __restrict__ feat,   // [N, 256]
    const float* __restrict__ w,      // [256, 64]
    const int*  __restrict__ active,  // [1]
    float* __restrict__ sup,          // [N, 64]
    int N)
{
    __shared__ float wsh[IN_F * OUT_F];   // 64 KB
    {
        const float4* src = (const float4*)w;
        float4* dst = (float4*)wsh;
        #pragma unroll
        for (int i = 0; i < (IN_F * OUT_F / 4) / 256; ++i)
            dst[i * 256 + threadIdx.x] = src[i * 256 + threadIdx.x];
    }
    __syncthreads();

    int wv   = __builtin_amdgcn_readfirstlane((int)(threadIdx.x >> 6));
    int lane = threadIdx.x & 63;
    int node0 = (blockIdx.x * 4 + wv) * NPW;
    if (node0 >= N) return;

    float acc[NPW];
    #pragma unroll
    for (int j = 0; j < NPW; ++j) acc[j] = 0.0f;

    const float* arow = feat + (size_t)node0 * IN_F;   // wave-uniform base
    for (int k = 0; k < IN_F; k += 4) {
        float w0 = wsh[(k + 0) * OUT_F + lane];
        float w1 = wsh[(k + 1) * OUT_F + lane];
        float w2 = wsh[(k + 2) * OUT_F + lane];
        float w3 = wsh[(k + 3) * OUT_F + lane];
        #pragma unroll
        for (int j = 0; j < NPW; ++j) {
            const float* a = arow + j * IN_F + k;      // uniform -> s_load_dwordx4
            acc[j] = fmaf(a[0], w0, acc[j]);
            acc[j] = fmaf(a[1], w1, acc[j]);
            acc[j] = fmaf(a[2], w2, acc[j]);
            acc[j] = fmaf(a[3], w3, acc[j]);
        }
    }

    int act = __builtin_amdgcn_readfirstlane(active[0]);
    #pragma unroll
    for (int j = 0; j < NPW; ++j) {
        float v = acc[j];
        if (act) v = tanhf(v);
        sup[(size_t)(node0 + j) * OUT_F + lane] = v;
    }
}

// ---------------------------------------------------------------------------
// 3. SpMM: out[r,:] = sum_{e in row r} vals[e] * x[cols[e],:]
//    One wave per row; lane = feature column (coalesced 256B gather/edge).
//    If row_ptr == null, find the edge range by binary search on sorted rows.
// ---------------------------------------------------------------------------
__device__ inline int lower_bound(const int* __restrict__ a, int n, int key) {
    int lo = 0, hi = n;
    while (lo < hi) {
        int mid = (lo + hi) >> 1;
        if (a[mid] < key) lo = mid + 1; else hi = mid;
    }
    return lo;
}

__global__ __launch_bounds__(256) void spmm_kernel(
    const int* __restrict__ row_ptr,   // [N+1] or null
    const int* __restrict__ rows,      // [E] sorted (used if row_ptr null)
    const int* __restrict__ cols,      // [E]
    const float* __restrict__ vals,    // [E]
    const float* __restrict__ x,       // [N, 64]
    float* __restrict__ out,           // [N, 64]
    int N, int E)
{
    int wv   = __builtin_amdgcn_readfirstlane((int)(threadIdx.x >> 6));
    int row  = blockIdx.x * 4 + wv;
    int lane = threadIdx.x & 63;
    if (row >= N) return;

    int s, e;
    if (row_ptr) {
        s = row_ptr[row];
        e = row_ptr[row + 1];
    } else {
        s = lower_bound(rows, E, row);
        e = lower_bound(rows, E, row + 1);
    }

    float acc = 0.0f;
    for (int i = s; i < e; ++i) {
        int   c = cols[i];      // wave-uniform -> scalar load
        float v = vals[i];      // wave-uniform
        acc = fmaf(v, x[(size_t)c * OUT_F + lane], acc);
    }
    out[(size_t)row * OUT_F + lane] = acc;
}

// ---------------------------------------------------------------------------
extern "C" void kernel_launch(void* const* d_in, const int* in_sizes, int n_in,
                              void* d_out, int out_size, void* d_ws, size_t ws_size,
                              hipStream_t stream) {
    const float* feat   = (const float*)d_in[0];   // [N,256] fp32
    const float* w      = (const float*)d_in[1];   // [256,64] fp32
    const int*   rows   = (const int*)d_in[2];     // [E] sorted
    const int*   cols   = (const int*)d_in[3];     // [E]
    const float* vals   = (const float*)d_in[4];   // [E] fp32
    const int*   active = (const int*)d_in[5];     // [1]

    const int N = in_sizes[0] / IN_F;   // 100000
    const int E = in_sizes[2];          // 1600000

    float* out = (float*)d_out;                    // [output | az], fp32
    float* az  = out + (size_t)N * OUT_F;

    // Workspace: row_ptr (N+1 ints) then fp32 support if room; else az-half
    // of d_out doubles as support scratch (spmm1 finishes reading it before
    // spmm2 overwrites az — same-stream serialization).
    size_t rp_bytes  = (((size_t)(N + 1) * sizeof(int)) + 255) & ~(size_t)255;
    size_t sup_bytes = (size_t)N * OUT_F * sizeof(float);
    char* ws = (char*)d_ws;
    int*   row_ptr = (ws_size >= rp_bytes) ? (int*)ws : nullptr;
    size_t rp_used = row_ptr ? rp_bytes : 0;
    float* sup = (ws_size >= rp_used + sup_bytes) ? (float*)(ws + rp_used) : az;

    if (row_ptr) {
        int threads = N + 1;
        rowptr_kernel<<<(threads + 255) / 256, 256, 0, stream>>>(rows, row_ptr, N, E);
    }

    {   // support = tanh(features @ weight)
        int blocks = (N + 4 * NPW - 1) / (4 * NPW);
        gemm_tanh_kernel<<<blocks, 256, 0, stream>>>(feat, w, active, sup, N);
    }

    int spmm_blocks = (N + 3) / 4;
    // output = A @ support
    spmm_kernel<<<spmm_blocks, 256, 0, stream>>>(row_ptr, rows, cols, vals, sup, out, N, E);
    // az = A @ output
    spmm_kernel<<<spmm_blocks, 256, 0, stream>>>(row_ptr, rows, cols, vals, out, az, N, E);
}

// Round 3
// 336.526 us; speedup vs baseline: 1.8305x; 1.8305x over previous
//
#include <hip/hip_runtime.h>
#include <hip/hip_bf16.h>
#include <math.h>

#define IN_F  256
#define OUT_F 64

typedef __attribute__((ext_vector_type(4))) float f32x4;

// GEMM tiling
#define TN   128          // nodes per block
#define KC   32           // k-chunk
#define FPAD 36           // feat_sh row stride (floats): pad 32->36, within-wave
                          // node stride 1 -> banks {0,4,8,12}, conflict-free b128

// ---------------------------------------------------------------------------
// 1. CSR row_ptr from sorted rows: row_ptr[r] = lower_bound(rows, r)
// ---------------------------------------------------------------------------
__global__ void rowptr_kernel(const int* __restrict__ rows,
                              int* __restrict__ row_ptr,
                              int n_rows, int n_edges) {
    int r = blockIdx.x * blockDim.x + threadIdx.x;
    if (r > n_rows) return;
    if (r == n_rows) { row_ptr[n_rows] = n_edges; return; }
    int lo = 0, hi = n_edges;
    while (lo < hi) {
        int mid = (lo + hi) >> 1;
        if (rows[mid] < r) lo = mid + 1; else hi = mid;
    }
    row_ptr[r] = lo;
}

// ---------------------------------------------------------------------------
// 2. support = tanh(features @ weight) — LDS-tiled fp32 vector GEMM.
//    Block: 128 nodes x 64 cols. Thread (tx=t&15, ty=t>>4):
//      cols 4*tx..4*tx+3, nodes {16*j + ty}, j=0..7  (32 accumulators).
//    Per k-chunk (32): stage feat[128][32] (padded) + w[32][64] via float4.
//    Inner 4-k group: 8 feat b128 + 4 w b128 per thread feed 128 FMAs.
// ---------------------------------------------------------------------------
__global__ __launch_bounds__(256) void gemm_tanh_kernel(
    const float* __restrict__ feat,   // [N, 256]
    const float* __restrict__ w,      // [256, 64]
    const int*  __restrict__ active,  // [1]
    float* __restrict__ sup,          // [N, 64]
    int N)
{
    __shared__ float feat_sh[TN * FPAD];    // 18432 B
    __shared__ float w_sh[KC * OUT_F];      //  8192 B

    const int t  = threadIdx.x;
    const int tx = t & 15;       // col group
    const int ty = t >> 4;       // node-within-16 group
    const int node_base = blockIdx.x * TN;

    f32x4 acc[8];
    #pragma unroll
    for (int j = 0; j < 8; ++j) acc[j] = (f32x4)0.0f;

    for (int k0 = 0; k0 < IN_F; k0 += KC) {
        // stage feat tile: 128 nodes x 32 k = 1024 float4; 4 per thread
        #pragma unroll
        for (int r = 0; r < 4; ++r) {
            int idx  = r * 256 + t;          // 0..1023
            int nd   = idx >> 3;             // node in tile
            int off  = (idx & 7) << 2;       // k offset (float4)
            int gn   = node_base + nd;
            if (gn > N - 1) gn = N - 1;      // clamp (OOB rows never stored)
            f32x4 v = *(const f32x4*)(feat + (size_t)gn * IN_F + k0 + off);
            *(f32x4*)(&feat_sh[nd * FPAD + off]) = v;
        }
        // stage w chunk: 32 x 64 = 512 float4 contiguous; 2 per thread
        #pragma unroll
        for (int r = 0; r < 2; ++r) {
            int idx = r * 256 + t;           // 0..511
            *(f32x4*)(&w_sh[idx * 4]) = *(const f32x4*)(w + (size_t)k0 * OUT_F + idx * 4);
        }
        __syncthreads();

        #pragma unroll
        for (int kk = 0; kk < KC; kk += 4) {
            f32x4 wf[4];
            #pragma unroll
            for (int jj = 0; jj < 4; ++jj)
                wf[jj] = *(const f32x4*)(&w_sh[(kk + jj) * OUT_F + tx * 4]);
            f32x4 ff[8];
            #pragma unroll
            for (int j = 0; j < 8; ++j)
                ff[j] = *(const f32x4*)(&feat_sh[(j * 16 + ty) * FPAD + kk]);
            #pragma unroll
            for (int j = 0; j < 8; ++j) {
                acc[j] += wf[0] * ff[j][0];
                acc[j] += wf[1] * ff[j][1];
                acc[j] += wf[2] * ff[j][2];
                acc[j] += wf[3] * ff[j][3];
            }
        }
        __syncthreads();
    }

    int act = __builtin_amdgcn_readfirstlane(active[0]);
    #pragma unroll
    for (int j = 0; j < 8; ++j) {
        int node = node_base + j * 16 + ty;
        if (node >= N) continue;
        f32x4 v = acc[j];
        if (act) {
            v[0] = tanhf(v[0]); v[1] = tanhf(v[1]);
            v[2] = tanhf(v[2]); v[3] = tanhf(v[3]);
        }
        *(f32x4*)(sup + (size_t)node * OUT_F + tx * 4) = v;
    }
}

// ---------------------------------------------------------------------------
// 3. SpMM: out[r,:] = sum_{e in row r} vals[e] * x[cols[e],:]
//    One wave per row; lane = col (coalesced 256B gather/edge); 4 edges in
//    flight via manual unroll. Edge metadata is wave-uniform -> scalar loads.
// ---------------------------------------------------------------------------
__device__ inline int lower_bound(const int* __restrict__ a, int n, int key) {
    int lo = 0, hi = n;
    while (lo < hi) {
        int mid = (lo + hi) >> 1;
        if (a[mid] < key) lo = mid + 1; else hi = mid;
    }
    return lo;
}

__global__ __launch_bounds__(256) void spmm_kernel(
    const int* __restrict__ row_ptr,   // [N+1] or null
    const int* __restrict__ rows,      // [E] sorted (fallback)
    const int* __restrict__ cols,      // [E]
    const float* __restrict__ vals,    // [E]
    const float* __restrict__ x,       // [N, 64]
    float* __restrict__ out,           // [N, 64]
    int N, int E)
{
    int wv   = __builtin_amdgcn_readfirstlane((int)(threadIdx.x >> 6));
    int row  = blockIdx.x * 4 + wv;
    int lane = threadIdx.x & 63;
    if (row >= N) return;

    int s, e;
    if (row_ptr) {
        s = row_ptr[row];
        e = row_ptr[row + 1];
    } else {
        s = lower_bound(rows, E, row);
        e = lower_bound(rows, E, row + 1);
    }

    float acc = 0.0f;
    int i = s;
    for (; i + 3 < e; i += 4) {
        int   c0 = cols[i],     c1 = cols[i + 1];
        int   c2 = cols[i + 2], c3 = cols[i + 3];
        float v0 = vals[i],     v1 = vals[i + 1];
        float v2 = vals[i + 2], v3 = vals[i + 3];
        float x0 = x[(size_t)c0 * OUT_F + lane];
        float x1 = x[(size_t)c1 * OUT_F + lane];
        float x2 = x[(size_t)c2 * OUT_F + lane];
        float x3 = x[(size_t)c3 * OUT_F + lane];
        acc = fmaf(v0, x0, acc);
        acc = fmaf(v1, x1, acc);
        acc = fmaf(v2, x2, acc);
        acc = fmaf(v3, x3, acc);
    }
    for (; i < e; ++i)
        acc = fmaf(vals[i], x[(size_t)cols[i] * OUT_F + lane], acc);

    out[(size_t)row * OUT_F + lane] = acc;
}

// ---------------------------------------------------------------------------
extern "C" void kernel_launch(void* const* d_in, const int* in_sizes, int n_in,
                              void* d_out, int out_size, void* d_ws, size_t ws_size,
                              hipStream_t stream) {
    const float* feat   = (const float*)d_in[0];   // [N,256] fp32
    const float* w      = (const float*)d_in[1];   // [256,64] fp32
    const int*   rows   = (const int*)d_in[2];     // [E] sorted
    const int*   cols   = (const int*)d_in[3];     // [E]
    const float* vals   = (const float*)d_in[4];   // [E] fp32
    const int*   active = (const int*)d_in[5];     // [1]

    const int N = in_sizes[0] / IN_F;   // 100000
    const int E = in_sizes[2];          // 1600000

    float* out = (float*)d_out;                    // [output | az], fp32
    float* az  = out + (size_t)N * OUT_F;

    // Workspace: row_ptr (N+1 ints) then fp32 support if room; else az-half
    // of d_out doubles as support scratch (stream-serialized, safe).
    size_t rp_bytes  = (((size_t)(N + 1) * sizeof(int)) + 255) & ~(size_t)255;
    size_t sup_bytes = (size_t)N * OUT_F * sizeof(float);
    char* ws = (char*)d_ws;
    int*   row_ptr = (ws_size >= rp_bytes) ? (int*)ws : nullptr;
    size_t rp_used = row_ptr ? rp_bytes : 0;
    float* sup = (ws_size >= rp_used + sup_bytes) ? (float*)(ws + rp_used) : az;

    if (row_ptr) {
        int threads = N + 1;
        rowptr_kernel<<<(threads + 255) / 256, 256, 0, stream>>>(rows, row_ptr, N, E);
    }

    {   // support = tanh(features @ weight)
        int blocks = (N + TN - 1) / TN;
        gemm_tanh_kernel<<<blocks, 256, 0, stream>>>(feat, w, active, sup, N);
    }

    int spmm_blocks = (N + 3) / 4;
    // output = A @ support
    spmm_kernel<<<spmm_blocks, 256, 0, stream>>>(row_ptr, rows, cols, vals, sup, out, N, E);
    // az = A @ output
    spmm_kernel<<<spmm_blocks, 256, 0, stream>>>(row_ptr, rows, cols, vals, out, az, N, E);
}

// Round 4
// 298.522 us; speedup vs baseline: 2.0635x; 1.1273x over previous
//
#include <hip/hip_runtime.h>
#include <hip/hip_bf16.h>
#include <math.h>

#define IN_F  256
#define OUT_F 64
#define PD    264      // w_t row stride in bf16 elems (264*2=528B: min-time b128 frag reads)

typedef __attribute__((ext_vector_type(8))) short bf16x8;
typedef __attribute__((ext_vector_type(4))) float f32x4;

__device__ inline unsigned short f2b(float x) {
    union { __hip_bfloat16 h; unsigned short u; } cv;
    cv.h = __float2bfloat16(x);
    return cv.u;
}
__device__ inline float b2f_lo(unsigned int u) { return __uint_as_float(u << 16); }
__device__ inline float b2f_hi(unsigned int u) { return __uint_as_float(u & 0xffff0000u); }

// ---------------------------------------------------------------------------
// 1. CSR row_ptr from sorted rows
// ---------------------------------------------------------------------------
__global__ void rowptr_kernel(const int* __restrict__ rows,
                              int* __restrict__ row_ptr,
                              int n_rows, int n_edges) {
    int r = blockIdx.x * blockDim.x + threadIdx.x;
    if (r > n_rows) return;
    if (r == n_rows) { row_ptr[n_rows] = n_edges; return; }
    int lo = 0, hi = n_edges;
    while (lo < hi) {
        int mid = (lo + hi) >> 1;
        if (rows[mid] < r) lo = mid + 1; else hi = mid;
    }
    row_ptr[r] = lo;
}

// ---------------------------------------------------------------------------
// 2. sup_bf = bf16(tanh(features @ weight)) — MFMA bf16, fp32 feat cvt on the fly.
//    Wave = 64 nodes (4 m-tiles of 16); block = 4 waves = 256 nodes.
//    A-frag: A[m=lane&15][k=quad*8+j] from global (16 rows x 64B segments/instr).
//    B-frag: one ds_read_b128 from transposed bf16 weight in LDS.
//    C/D: col=lane&15, row=quad*4+reg (measured m89/m91).
// ---------------------------------------------------------------------------
__global__ __launch_bounds__(256) void gemm_tanh_kernel(
    const float* __restrict__ feat,      // [N, 256]
    const float* __restrict__ w,         // [256, 64]
    const int*  __restrict__ active,     // [1]
    unsigned short* __restrict__ sup_bf, // [N, 64] bf16 bits
    int N)
{
    __shared__ unsigned short wt[OUT_F * PD];   // 33792 B, wt[n*PD + k]

    const int t = threadIdx.x;
    // stage weight: fp32 [k][n] -> bf16 transposed [n][k]
    #pragma unroll
    for (int r = 0; r < 16; ++r) {
        int f = r * 256 + t;              // float4 index, 0..4095
        float4 v = ((const float4*)w)[f];
        int k = f >> 4;                   // 4f/64
        int n = (f & 15) << 2;            // 4f%64
        wt[(n + 0) * PD + k] = f2b(v.x);
        wt[(n + 1) * PD + k] = f2b(v.y);
        wt[(n + 2) * PD + k] = f2b(v.z);
        wt[(n + 3) * PD + k] = f2b(v.w);
    }
    __syncthreads();

    const int lane = t & 63;
    const int m    = lane & 15;
    const int quad = lane >> 4;
    const int node0 = blockIdx.x * 256 + (t >> 6) * 64;

    f32x4 acc[4][4];   // [mtile][ntile]
    #pragma unroll
    for (int a = 0; a < 4; ++a)
        #pragma unroll
        for (int b = 0; b < 4; ++b) acc[a][b] = (f32x4)0.0f;

    const float* arow[4];
    #pragma unroll
    for (int mt = 0; mt < 4; ++mt) {
        int nd = node0 + mt * 16 + m;
        if (nd > N - 1) nd = N - 1;       // clamp; OOB rows never stored
        arow[mt] = feat + (size_t)nd * IN_F;
    }

    for (int kt = 0; kt < 8; ++kt) {
        const int ko = kt * 32 + quad * 8;
        bf16x8 a[4];
        #pragma unroll
        for (int mt = 0; mt < 4; ++mt) {
            f32x4 lo = *(const f32x4*)(arow[mt] + ko);
            f32x4 hi = *(const f32x4*)(arow[mt] + ko + 4);
            bf16x8 av;
            av[0] = (short)f2b(lo[0]); av[1] = (short)f2b(lo[1]);
            av[2] = (short)f2b(lo[2]); av[3] = (short)f2b(lo[3]);
            av[4] = (short)f2b(hi[0]); av[5] = (short)f2b(hi[1]);
            av[6] = (short)f2b(hi[2]); av[7] = (short)f2b(hi[3]);
            a[mt] = av;
        }
        #pragma unroll
        for (int nt = 0; nt < 4; ++nt) {
            bf16x8 b = *(const bf16x8*)(&wt[(nt * 16 + m) * PD + ko]);
            #pragma unroll
            for (int mt = 0; mt < 4; ++mt)
                acc[mt][nt] = __builtin_amdgcn_mfma_f32_16x16x32_bf16(a[mt], b, acc[mt][nt], 0, 0, 0);
        }
    }

    int act = __builtin_amdgcn_readfirstlane(active[0]);
    #pragma unroll
    for (int mt = 0; mt < 4; ++mt) {
        #pragma unroll
        for (int r = 0; r < 4; ++r) {
            int node = node0 + mt * 16 + quad * 4 + r;
            if (node >= N) continue;
            #pragma unroll
            for (int nt = 0; nt < 4; ++nt) {
                float v = acc[mt][nt][r];
                if (act) v = tanhf(v);
                sup_bf[(size_t)node * OUT_F + nt * 16 + m] = f2b(v);
            }
        }
    }
}

// ---------------------------------------------------------------------------
// 3. SpMM: out[r,:] = sum_e vals[e] * x[cols[e],:]
//    Wave per row. Half-wave per edge (2 edges per gather instr), lane holds
//    2 cols; 4 pairs (8 edges) unrolled -> 4 gathers in flight. Edge metadata
//    wave-uniform -> s_load. Cross-half combine via shfl_xor(32).
//    XBF: gather source bf16 (4B/lane) else fp32 (8B/lane).
// ---------------------------------------------------------------------------
__device__ inline int lower_bound(const int* __restrict__ a, int n, int key) {
    int lo = 0, hi = n;
    while (lo < hi) {
        int mid = (lo + hi) >> 1;
        if (a[mid] < key) lo = mid + 1; else hi = mid;
    }
    return lo;
}

template <bool XBF>
__global__ __launch_bounds__(256) void spmm_kernel(
    const int* __restrict__ row_ptr,          // [N+1] or null
    const int* __restrict__ rows,             // [E] sorted (fallback)
    const int* __restrict__ cols,             // [E]
    const float* __restrict__ vals,           // [E]
    const void* __restrict__ x,               // [N,64] bf16 or fp32
    float* __restrict__ out,                  // [N,64] fp32
    unsigned short* __restrict__ out_bf,      // [N,64] bf16 or null
    int N, int E)
{
    const int wv   = __builtin_amdgcn_readfirstlane((int)(threadIdx.x >> 6));
    const int row  = blockIdx.x * 4 + wv;
    const int lane = threadIdx.x & 63;
    const int h    = lane >> 5;       // half
    const int l    = lane & 31;       // lane in half -> cols {2l, 2l+1}
    if (row >= N) return;

    int s, e;
    if (row_ptr) { s = row_ptr[row]; e = row_ptr[row + 1]; }
    else         { s = lower_bound(rows, E, row); e = lower_bound(rows, E, row + 1); }

    const unsigned short* xb = (const unsigned short*)x;
    const float*          xf = (const float*)x;

    float ax = 0.0f, ay = 0.0f;
    int i = s;
    for (; i + 8 <= e; i += 8) {
        #pragma unroll
        for (int p = 0; p < 4; ++p) {
            int   c0 = cols[i + 2 * p],     c1 = cols[i + 2 * p + 1];
            float v0 = vals[i + 2 * p],     v1 = vals[i + 2 * p + 1];
            int   c  = h ? c1 : c0;
            float v  = h ? v1 : v0;
            if (XBF) {
                unsigned int r2 = *(const unsigned int*)(xb + (size_t)c * OUT_F + 2 * l);
                ax = fmaf(v, b2f_lo(r2), ax);
                ay = fmaf(v, b2f_hi(r2), ay);
            } else {
                float2 r2 = *(const float2*)(xf + (size_t)c * OUT_F + 2 * l);
                ax = fmaf(v, r2.x, ax);
                ay = fmaf(v, r2.y, ay);
            }
        }
    }
    for (; i + 2 <= e; i += 2) {
        int   c0 = cols[i],  c1 = cols[i + 1];
        float v0 = vals[i],  v1 = vals[i + 1];
        int   c  = h ? c1 : c0;
        float v  = h ? v1 : v0;
        if (XBF) {
            unsigned int r2 = *(const unsigned int*)(xb + (size_t)c * OUT_F + 2 * l);
            ax = fmaf(v, b2f_lo(r2), ax);
            ay = fmaf(v, b2f_hi(r2), ay);
        } else {
            float2 r2 = *(const float2*)(xf + (size_t)c * OUT_F + 2 * l);
            ax = fmaf(v, r2.x, ax);
            ay = fmaf(v, r2.y, ay);
        }
    }
    if (i < e) {   // odd edge: half1 contributes 0
        int   c = cols[i];
        float v = h ? 0.0f : vals[i];
        if (XBF) {
            unsigned int r2 = *(const unsigned int*)(xb + (size_t)c * OUT_F + 2 * l);
            ax = fmaf(v, b2f_lo(r2), ax);
            ay = fmaf(v, b2f_hi(r2), ay);
        } else {
            float2 r2 = *(const float2*)(xf + (size_t)c * OUT_F + 2 * l);
            ax = fmaf(v, r2.x, ax);
            ay = fmaf(v, r2.y, ay);
        }
    }

    // combine halves (both halves accumulate the same row)
    ax += __shfl_xor(ax, 32, 64);
    ay += __shfl_xor(ay, 32, 64);

    if (h == 0) {
        size_t base = (size_t)row * OUT_F + 2 * l;
        *(float2*)(out + base) = make_float2(ax, ay);
        if (out_bf) {
            unsigned int pk = (unsigned int)f2b(ax) | ((unsigned int)f2b(ay) << 16);
            *(unsigned int*)(out_bf + base) = pk;
        }
    }
}

// ---------------------------------------------------------------------------
extern "C" void kernel_launch(void* const* d_in, const int* in_sizes, int n_in,
                              void* d_out, int out_size, void* d_ws, size_t ws_size,
                              hipStream_t stream) {
    const float* feat   = (const float*)d_in[0];   // [N,256] fp32
    const float* w      = (const float*)d_in[1];   // [256,64] fp32
    const int*   rows   = (const int*)d_in[2];     // [E] sorted
    const int*   cols   = (const int*)d_in[3];     // [E]
    const float* vals   = (const float*)d_in[4];   // [E] fp32
    const int*   active = (const int*)d_in[5];     // [1]

    const int N = in_sizes[0] / IN_F;   // 100000
    const int E = in_sizes[2];          // 1600000

    float* out = (float*)d_out;                    // [output | az] fp32
    float* az  = out + (size_t)N * OUT_F;

    // Workspace tiers
    size_t rp_bytes = (((size_t)(N + 1) * sizeof(int)) + 255) & ~(size_t)255;
    size_t bf_bytes = (((size_t)N * OUT_F * sizeof(unsigned short)) + 255) & ~(size_t)255;
    char* ws = (char*)d_ws;

    int* row_ptr = (ws_size >= rp_bytes) ? (int*)ws : nullptr;
    size_t used = row_ptr ? rp_bytes : 0;

    unsigned short* sup_bf;
    unsigned short* mid_bf = nullptr;   // bf16 copy of `output` for spmm2 gather
    if (ws_size >= used + 2 * bf_bytes) {
        sup_bf = (unsigned short*)(ws + used);
        mid_bf = (unsigned short*)(ws + used + bf_bytes);
    } else if (ws_size >= used + bf_bytes) {
        sup_bf = (unsigned short*)(ws + used);
    } else {
        // az half of d_out as bf16 scratch (dead before spmm2 writes az)
        sup_bf = (unsigned short*)az;
    }

    if (row_ptr) {
        int threads = N + 1;
        rowptr_kernel<<<(threads + 255) / 256, 256, 0, stream>>>(rows, row_ptr, N, E);
    }

    {   // sup_bf = bf16(tanh(feat @ w))
        int blocks = (N + 255) / 256;
        gemm_tanh_kernel<<<blocks, 256, 0, stream>>>(feat, w, active, sup_bf, N);
    }

    int spmm_blocks = (N + 3) / 4;
    // output = A @ support   (gather bf16; also emit bf16 copy if we have room)
    spmm_kernel<true><<<spmm_blocks, 256, 0, stream>>>(
        row_ptr, rows, cols, vals, sup_bf, out, mid_bf, N, E);
    // az = A @ output
    if (mid_bf) {
        spmm_kernel<true><<<spmm_blocks, 256, 0, stream>>>(
            row_ptr, rows, cols, vals, mid_bf, az, nullptr, N, E);
    } else {
        spmm_kernel<false><<<spmm_blocks, 256, 0, stream>>>(
            row_ptr, rows, cols, vals, out, az, nullptr, N, E);
    }
}